// Round 1
// baseline (48.501 us; speedup 1.0000x reference)
//
#include <hip/hip_runtime.h>
#include <hip/hip_bf16.h>

// Problem constants (from reference): (8, 2048, 128) fp32 x2 -> (8, 2048, 2048) fp32
#define BATCH 8
#define RROWS 2048
#define DDIM  128
#define BM    128
#define BN    128

using f32x4 = __attribute__((ext_vector_type(4))) float;
using s16x8 = __attribute__((ext_vector_type(8))) short;
using u16x4 = __attribute__((ext_vector_type(4))) unsigned short;

// fp32 -> bf16 round-to-nearest-even (data is finite normal floats; NaN path not needed)
__device__ __forceinline__ unsigned short f2bf(float f) {
    unsigned int u = __builtin_bit_cast(unsigned int, f);
    u += 0x7fffu + ((u >> 16) & 1u);
    return (unsigned short)(u >> 16);
}

__global__ __launch_bounds__(256, 2) void cosim_kernel(const float* __restrict__ m1,
                                                       const float* __restrict__ m2,
                                                       float* __restrict__ out) {
    // 64 KiB LDS: A panel (128x128 bf16) + B panel (128x128 bf16), XOR-swizzled rows
    __shared__ __align__(16) char lds[BM * DDIM * 2 + BN * DDIM * 2];
    char* As = lds;
    char* Bs = lds + BM * DDIM * 2;

    const int tid    = threadIdx.x;
    const int b      = blockIdx.z;
    const int tile_m = blockIdx.y;
    const int tile_n = blockIdx.x;

    const float* gA = m1 + ((size_t)b * RROWS + (size_t)tile_m * BM) * DDIM;
    const float* gB = m2 + ((size_t)b * RROWS + (size_t)tile_n * BN) * DDIM;

    // ---- Stage 1: load fp32 panels, L2-normalize rows, store bf16 to swizzled LDS ----
    // Each iteration: 8 rows fully processed; each row owned by one 32-lane group.
    // f = tid + k*256; row = f>>5 (32 float4 per row of 128 floats); c4 = f&31.
    #pragma unroll
    for (int k = 0; k < 16; ++k) {
        const int f  = tid + k * 256;
        const int r  = f >> 5;
        const int c4 = f & 31;

        const float4 va = *(const float4*)(gA + r * DDIM + c4 * 4);
        const float4 vb = *(const float4*)(gB + r * DDIM + c4 * 4);

        float sa = va.x * va.x + va.y * va.y + va.z * va.z + va.w * va.w;
        float sb = vb.x * vb.x + vb.y * vb.y + vb.z * vb.z + vb.w * vb.w;

        // reduce across the 32-lane group that owns this row (masks < 32 stay in-half)
        #pragma unroll
        for (int s = 1; s <= 16; s <<= 1) {
            sa += __shfl_xor(sa, s);
            sb += __shfl_xor(sb, s);
        }

        const float ia = rsqrtf(fmaxf(sa, 1e-8f));
        const float ib = rsqrtf(fmaxf(sb, 1e-8f));

        u16x4 pa, pb;
        pa[0] = f2bf(va.x * ia); pa[1] = f2bf(va.y * ia);
        pa[2] = f2bf(va.z * ia); pa[3] = f2bf(va.w * ia);
        pb[0] = f2bf(vb.x * ib); pb[1] = f2bf(vb.y * ib);
        pb[2] = f2bf(vb.z * ib); pb[3] = f2bf(vb.w * ib);

        const int byteoff = r * 256 + c4 * 8;          // row stride = 128 bf16 = 256 B
        const int swz     = byteoff ^ ((r & 7) << 4);  // XOR-swizzle 16B slots
        *(u16x4*)(As + swz) = pa;
        *(u16x4*)(Bs + swz) = pb;
    }

    __syncthreads();

    // ---- Stage 2: MFMA. 4 waves in 2x2 grid, each computes 64x64 of the 128x128 tile ----
    const int wave = tid >> 6;
    const int lane = tid & 63;
    const int wr   = wave >> 1;           // 0..1
    const int wc   = wave & 1;            // 0..1
    const int lrow = lane & 15;
    const int kb   = (lane >> 4) * 8;     // k sub-offset per lane quad: 0,8,16,24

    f32x4 acc[4][4];
    #pragma unroll
    for (int m = 0; m < 4; ++m)
        #pragma unroll
        for (int n = 0; n < 4; ++n)
            acc[m][n] = f32x4{0.f, 0.f, 0.f, 0.f};

    #pragma unroll
    for (int kk = 0; kk < 4; ++kk) {
        const int k = kk * 32 + kb;       // bf16 element index along K
        s16x8 af[4], bfr[4];
        #pragma unroll
        for (int m = 0; m < 4; ++m) {
            const int ra   = wr * 64 + m * 16 + lrow;
            const int offa = ra * 256 + k * 2;
            af[m] = *(const s16x8*)(As + (offa ^ ((ra & 7) << 4)));
            const int rb   = wc * 64 + m * 16 + lrow;
            const int offb = rb * 256 + k * 2;
            bfr[m] = *(const s16x8*)(Bs + (offb ^ ((rb & 7) << 4)));
        }
        #pragma unroll
        for (int m = 0; m < 4; ++m)
            #pragma unroll
            for (int n = 0; n < 4; ++n)
                acc[m][n] = __builtin_amdgcn_mfma_f32_16x16x32_bf16(af[m], bfr[n], acc[m][n], 0, 0, 0);
    }

    // ---- Stage 3: store. C/D layout: col = lane&15, row = (lane>>4)*4 + reg ----
    float* gout = out + (size_t)b * RROWS * RROWS;
    const int orow0 = tile_m * BM + wr * 64 + (lane >> 4) * 4;
    const int ocol0 = tile_n * BN + wc * 64 + lrow;

    #pragma unroll
    for (int m = 0; m < 4; ++m) {
        #pragma unroll
        for (int n = 0; n < 4; ++n) {
            const int row = orow0 + m * 16;
            const int col = ocol0 + n * 16;
            #pragma unroll
            for (int reg = 0; reg < 4; ++reg)
                gout[(size_t)(row + reg) * RROWS + col] = acc[m][n][reg];
        }
    }
}

extern "C" void kernel_launch(void* const* d_in, const int* in_sizes, int n_in,
                              void* d_out, int out_size, void* d_ws, size_t ws_size,
                              hipStream_t stream) {
    (void)in_sizes; (void)n_in; (void)d_ws; (void)ws_size; (void)out_size;
    const float* m1 = (const float*)d_in[0];
    const float* m2 = (const float*)d_in[1];
    float* out = (float*)d_out;

    dim3 grid(RROWS / BN, RROWS / BM, BATCH);
    cosim_kernel<<<grid, dim3(256), 0, stream>>>(m1, m2, out);
}

// Round 2
// 42.531 us; speedup vs baseline: 1.1404x; 1.1404x over previous
//
#include <hip/hip_runtime.h>
#include <hip/hip_bf16.h>

// Problem constants: (8, 2048, 128) fp32 x2 -> (8, 2048, 2048) fp32
#define BATCH 8
#define RROWS 2048
#define DDIM  128
#define BM    128
#define BN    128
#define NROWS (BATCH * RROWS)           // rows per matrix
#define WS_BYTES_PER_MAT ((size_t)NROWS * DDIM * 2)   // bf16

using f32x4 = __attribute__((ext_vector_type(4))) float;
using s16x8 = __attribute__((ext_vector_type(8))) short;
using u16x4 = __attribute__((ext_vector_type(4))) unsigned short;

// fp32 -> bf16 round-to-nearest-even (inputs are finite normals)
__device__ __forceinline__ unsigned short f2bf(float f) {
    unsigned int u = __builtin_bit_cast(unsigned int, f);
    u += 0x7fffu + ((u >> 16) & 1u);
    return (unsigned short)(u >> 16);
}

// ---------------- Kernel 1: L2-normalize rows of both matrices -> bf16 in ws ----------------
__global__ __launch_bounds__(256) void normalize_kernel(const float* __restrict__ m1,
                                                        const float* __restrict__ m2,
                                                        unsigned short* __restrict__ wsA,
                                                        unsigned short* __restrict__ wsB) {
    const int tid    = threadIdx.x;
    const int lane32 = tid & 31;
    const int row    = (blockIdx.x * 256 + tid) >> 5;   // one row per 32-lane group
    if (row >= NROWS) return;

    const size_t off = (size_t)row * DDIM + lane32 * 4;

    const float4 va = *(const float4*)(m1 + off);
    const float4 vb = *(const float4*)(m2 + off);
    float sa = va.x * va.x + va.y * va.y + va.z * va.z + va.w * va.w;
    float sb = vb.x * vb.x + vb.y * vb.y + vb.z * vb.z + vb.w * vb.w;
    #pragma unroll
    for (int s = 1; s <= 16; s <<= 1) {
        sa += __shfl_xor(sa, s);
        sb += __shfl_xor(sb, s);
    }
    const float ia = rsqrtf(fmaxf(sa, 1e-8f));
    const float ib = rsqrtf(fmaxf(sb, 1e-8f));

    u16x4 pa, pb;
    pa[0] = f2bf(va.x * ia); pa[1] = f2bf(va.y * ia);
    pa[2] = f2bf(va.z * ia); pa[3] = f2bf(va.w * ia);
    pb[0] = f2bf(vb.x * ib); pb[1] = f2bf(vb.y * ib);
    pb[2] = f2bf(vb.z * ib); pb[3] = f2bf(vb.w * ib);
    *(u16x4*)(wsA + off) = pa;
    *(u16x4*)(wsB + off) = pb;
}

// ---------------- Kernel 2: bf16 GEMM, global_load_lds staging with pre-swizzled source ----------------
__global__ __launch_bounds__(256, 2) void gemm_kernel(const unsigned short* __restrict__ wsA,
                                                      const unsigned short* __restrict__ wsB,
                                                      float* __restrict__ out) {
    __shared__ __align__(16) char lds[BM * DDIM * 2 + BN * DDIM * 2];  // 64 KiB
    char* As = lds;
    char* Bs = lds + BM * DDIM * 2;

    const int tid    = threadIdx.x;
    const int b      = blockIdx.z;
    const int tile_m = blockIdx.y;
    const int tile_n = blockIdx.x;
    const int wave   = tid >> 6;
    const int lane   = tid & 63;

    const char* gA = (const char*)(wsA + ((size_t)b * RROWS + (size_t)tile_m * BM) * DDIM);
    const char* gB = (const char*)(wsB + ((size_t)b * RROWS + (size_t)tile_n * BN) * DDIM);

    // Stage panels: 32 KiB each, 1 KiB per wave-issue. LDS dest is linear
    // (wave-uniform base + lane*16); the XOR-swizzle is applied by reading
    // the INVERSE-swizzled global address per lane (swizzle is an involution).
    #pragma unroll
    for (int it = 0; it < 8; ++it) {
        const int chunk = (wave * 8 + it) * 1024;
        const int L  = chunk + lane * 16;
        const int gl = L ^ (((L >> 8) & 7) << 4);
        __builtin_amdgcn_global_load_lds((const __attribute__((address_space(1))) void*)(gA + gl),
                                         (__attribute__((address_space(3))) void*)(As + chunk), 16, 0, 0);
        __builtin_amdgcn_global_load_lds((const __attribute__((address_space(1))) void*)(gB + gl),
                                         (__attribute__((address_space(3))) void*)(Bs + chunk), 16, 0, 0);
    }
    __syncthreads();

    // 4 waves in 2x2, each computes a 64x64 sub-tile
    const int wr   = wave >> 1;
    const int wc   = wave & 1;
    const int lrow = lane & 15;
    const int kb   = (lane >> 4) * 8;

    f32x4 acc[4][4];
    #pragma unroll
    for (int m = 0; m < 4; ++m)
        #pragma unroll
        for (int n = 0; n < 4; ++n)
            acc[m][n] = f32x4{0.f, 0.f, 0.f, 0.f};

    #pragma unroll
    for (int kk = 0; kk < 4; ++kk) {
        const int k = kk * 32 + kb;
        s16x8 af[4], bfr[4];
        #pragma unroll
        for (int m = 0; m < 4; ++m) {
            const int ra   = wr * 64 + m * 16 + lrow;
            const int offa = ra * 256 + k * 2;
            af[m] = *(const s16x8*)(As + (offa ^ ((ra & 7) << 4)));
            const int rb   = wc * 64 + m * 16 + lrow;
            const int offb = rb * 256 + k * 2;
            bfr[m] = *(const s16x8*)(Bs + (offb ^ ((rb & 7) << 4)));
        }
        #pragma unroll
        for (int m = 0; m < 4; ++m)
            #pragma unroll
            for (int n = 0; n < 4; ++n)
                acc[m][n] = __builtin_amdgcn_mfma_f32_16x16x32_bf16(af[m], bfr[n], acc[m][n], 0, 0, 0);
    }

    // Store. C/D layout: col = lane&15, row = (lane>>4)*4 + reg
    float* gout = out + (size_t)b * RROWS * RROWS;
    const int orow0 = tile_m * BM + wr * 64 + (lane >> 4) * 4;
    const int ocol0 = tile_n * BN + wc * 64 + lrow;

    #pragma unroll
    for (int m = 0; m < 4; ++m) {
        #pragma unroll
        for (int n = 0; n < 4; ++n) {
            const int row = orow0 + m * 16;
            const int col = ocol0 + n * 16;
            #pragma unroll
            for (int reg = 0; reg < 4; ++reg)
                gout[(size_t)(row + reg) * RROWS + col] = acc[m][n][reg];
        }
    }
}

// ---------------- Fallback: round-1 fused kernel (used if ws too small) ----------------
__global__ __launch_bounds__(256, 2) void cosim_kernel(const float* __restrict__ m1,
                                                       const float* __restrict__ m2,
                                                       float* __restrict__ out) {
    __shared__ __align__(16) char lds[BM * DDIM * 2 + BN * DDIM * 2];
    char* As = lds;
    char* Bs = lds + BM * DDIM * 2;

    const int tid    = threadIdx.x;
    const int b      = blockIdx.z;
    const int tile_m = blockIdx.y;
    const int tile_n = blockIdx.x;

    const float* gA = m1 + ((size_t)b * RROWS + (size_t)tile_m * BM) * DDIM;
    const float* gB = m2 + ((size_t)b * RROWS + (size_t)tile_n * BN) * DDIM;

    #pragma unroll
    for (int k = 0; k < 16; ++k) {
        const int f  = tid + k * 256;
        const int r  = f >> 5;
        const int c4 = f & 31;

        const float4 va = *(const float4*)(gA + r * DDIM + c4 * 4);
        const float4 vb = *(const float4*)(gB + r * DDIM + c4 * 4);

        float sa = va.x * va.x + va.y * va.y + va.z * va.z + va.w * va.w;
        float sb = vb.x * vb.x + vb.y * vb.y + vb.z * vb.z + vb.w * vb.w;
        #pragma unroll
        for (int s = 1; s <= 16; s <<= 1) {
            sa += __shfl_xor(sa, s);
            sb += __shfl_xor(sb, s);
        }
        const float ia = rsqrtf(fmaxf(sa, 1e-8f));
        const float ib = rsqrtf(fmaxf(sb, 1e-8f));

        u16x4 pa, pb;
        pa[0] = f2bf(va.x * ia); pa[1] = f2bf(va.y * ia);
        pa[2] = f2bf(va.z * ia); pa[3] = f2bf(va.w * ia);
        pb[0] = f2bf(vb.x * ib); pb[1] = f2bf(vb.y * ib);
        pb[2] = f2bf(vb.z * ib); pb[3] = f2bf(vb.w * ib);

        const int byteoff = r * 256 + c4 * 8;
        const int swz     = byteoff ^ ((r & 7) << 4);
        *(u16x4*)(As + swz) = pa;
        *(u16x4*)(Bs + swz) = pb;
    }
    __syncthreads();

    const int wave = tid >> 6;
    const int lane = tid & 63;
    const int wr   = wave >> 1;
    const int wc   = wave & 1;
    const int lrow = lane & 15;
    const int kb   = (lane >> 4) * 8;

    f32x4 acc[4][4];
    #pragma unroll
    for (int m = 0; m < 4; ++m)
        #pragma unroll
        for (int n = 0; n < 4; ++n)
            acc[m][n] = f32x4{0.f, 0.f, 0.f, 0.f};

    #pragma unroll
    for (int kk = 0; kk < 4; ++kk) {
        const int k = kk * 32 + kb;
        s16x8 af[4], bfr[4];
        #pragma unroll
        for (int m = 0; m < 4; ++m) {
            const int ra   = wr * 64 + m * 16 + lrow;
            const int offa = ra * 256 + k * 2;
            af[m] = *(const s16x8*)(As + (offa ^ ((ra & 7) << 4)));
            const int rb   = wc * 64 + m * 16 + lrow;
            const int offb = rb * 256 + k * 2;
            bfr[m] = *(const s16x8*)(Bs + (offb ^ ((rb & 7) << 4)));
        }
        #pragma unroll
        for (int m = 0; m < 4; ++m)
            #pragma unroll
            for (int n = 0; n < 4; ++n)
                acc[m][n] = __builtin_amdgcn_mfma_f32_16x16x32_bf16(af[m], bfr[n], acc[m][n], 0, 0, 0);
    }

    float* gout = out + (size_t)b * RROWS * RROWS;
    const int orow0 = tile_m * BM + wr * 64 + (lane >> 4) * 4;
    const int ocol0 = tile_n * BN + wc * 64 + lrow;

    #pragma unroll
    for (int m = 0; m < 4; ++m) {
        #pragma unroll
        for (int n = 0; n < 4; ++n) {
            const int row = orow0 + m * 16;
            const int col = ocol0 + n * 16;
            #pragma unroll
            for (int reg = 0; reg < 4; ++reg)
                gout[(size_t)(row + reg) * RROWS + col] = acc[m][n][reg];
        }
    }
}

extern "C" void kernel_launch(void* const* d_in, const int* in_sizes, int n_in,
                              void* d_out, int out_size, void* d_ws, size_t ws_size,
                              hipStream_t stream) {
    (void)in_sizes; (void)n_in; (void)out_size;
    const float* m1 = (const float*)d_in[0];
    const float* m2 = (const float*)d_in[1];
    float* out = (float*)d_out;

    if (ws_size >= 2 * WS_BYTES_PER_MAT) {
        unsigned short* wsA = (unsigned short*)d_ws;
        unsigned short* wsB = wsA + (size_t)NROWS * DDIM;
        normalize_kernel<<<dim3(NROWS / 8), dim3(256), 0, stream>>>(m1, m2, wsA, wsB);
        dim3 grid(RROWS / BN, RROWS / BM, BATCH);
        gemm_kernel<<<grid, dim3(256), 0, stream>>>(wsA, wsB, out);
    } else {
        dim3 grid(RROWS / BN, RROWS / BM, BATCH);
        cosim_kernel<<<grid, dim3(256), 0, stream>>>(m1, m2, out);
    }
}